// Round 3
// baseline (201.934 us; speedup 1.0000x reference)
//
#include <hip/hip_runtime.h>
#include <hip/hip_bf16.h>

#define N1 8192
#define N2 16384
#define DIM 256
#define NSPLIT 4
#define BM 64
#define BN 64
#define COLS_PER_SPLIT (N2 / NSPLIT)   // 4096
#define NPART (NSPLIT * 4)             // partial top3 sets per row

typedef short v8s  __attribute__((ext_vector_type(8)));   // 8 x bf16 bits (4 VGPR)
typedef float f32x4 __attribute__((ext_vector_type(4)));

__device__ __forceinline__ void top3_insert(float v, float& t0, float& t1, float& t2) {
    // invariant t0 >= t1 >= t2; 4 VALU ops (max, med3, min, max)
    float nt1 = __builtin_amdgcn_fmed3f(t0, t1, v);
    float nt2 = fmaxf(t2, fminf(t1, v));
    t0 = fmaxf(t0, v);
    t1 = nt1;
    t2 = nt2;
}

// One wave per row over A then B: fp32 sumsq, rsqrt, emit bf16 normalized row.
__global__ __launch_bounds__(256) void normalize_kernel(
        const float* __restrict__ inA, const float* __restrict__ inB,
        __hip_bfloat16* __restrict__ outA, __hip_bfloat16* __restrict__ outB) {
    const int gw   = blockIdx.x * 4 + (threadIdx.x >> 6);   // global wave id = row id
    const int lane = threadIdx.x & 63;
    const float* in;
    __hip_bfloat16* out;
    int row;
    if (gw < N1) { in = inA; out = outA; row = gw; }
    else         { in = inB; out = outB; row = gw - N1; }
    const float4 v = *(const float4*)(in + (size_t)row * DIM + lane * 4);
    float s = v.x * v.x + v.y * v.y + v.z * v.z + v.w * v.w;
    #pragma unroll
    for (int off = 32; off; off >>= 1) s += __shfl_xor(s, off, 64);
    const float inv = 1.0f / sqrtf(s);
    __hip_bfloat16 o[4];
    o[0] = __float2bfloat16(v.x * inv);
    o[1] = __float2bfloat16(v.y * inv);
    o[2] = __float2bfloat16(v.z * inv);
    o[3] = __float2bfloat16(v.w * inv);
    *(uint2*)(out + (size_t)row * DIM + lane * 4) = *(uint2*)o;
}

// Block: 4 waves. 64 rows of A pinned in registers (128 VGPR/lane, pinned
// live-in to every iteration so the allocator cannot reload them).
// Wave w covers cols {col0 + 64*it + (lane&15)}; streaming top3 per (lane,row).
__global__ __launch_bounds__(256, 2) void gemm_top3_kernel(
        const __hip_bfloat16* __restrict__ A, const __hip_bfloat16* __restrict__ B,
        float* __restrict__ partial) {
    const int tid   = threadIdx.x;
    const int wave  = tid >> 6;
    const int lane  = tid & 63;
    const int lo    = lane & 15;
    const int quad  = lane >> 4;
    const int rb    = blockIdx.x % (N1 / BM);
    const int split = blockIdx.x / (N1 / BM);
    const int row0  = rb * BM;
    const int col0  = split * COLS_PER_SPLIT + wave * 16;

    // A fragments: afrag[rt][ks] -> rows row0+rt*16+lo, k = ks*32 + quad*8 + j
    v8s afrag[4][8];
    #pragma unroll
    for (int rt = 0; rt < 4; rt++) {
        const __hip_bfloat16* ap = A + (size_t)(row0 + rt * 16 + lo) * DIM + quad * 8;
        #pragma unroll
        for (int ks = 0; ks < 8; ks++)
            afrag[rt][ks] = *(const v8s*)(ap + ks * 32);
    }

    float t0[16], t1[16], t2[16];
    #pragma unroll
    for (int i = 0; i < 16; i++) { t0[i] = -1e30f; t1[i] = -1e30f; t2[i] = -1e30f; }

    const __hip_bfloat16* bp = B + (size_t)(col0 + lo) * DIM + quad * 8;

    const f32x4 zf = (f32x4){0.f, 0.f, 0.f, 0.f};

    // depth-2 rolling B prefetch (8 VGPR in flight)
    v8s bq0 = *(const v8s*)(bp);
    v8s bq1 = *(const v8s*)(bp + 32);

    for (int it = 0; it < COLS_PER_SPLIT / BN; ++it) {
        // Pin A live-in to THIS iteration: reloading is now pointless.
        #pragma unroll
        for (int rt = 0; rt < 4; rt++)
            #pragma unroll
            for (int ks = 0; ks < 8; ks++)
                asm volatile("" : "+v"(afrag[rt][ks]));

        f32x4 acc[4];
        #pragma unroll
        for (int ks = 0; ks < 8; ks++) {
            // prefetch position (it, ks+2), wrapping into next iter's k=0,1.
            // Tail iteration prefetches past the split (dead values; lands in
            // ws scratch, never consumed).
            const __hip_bfloat16* nb = (ks < 6) ? (bp + (ks + 2) * 32)
                                                : (bp + (size_t)BN * DIM + (ks - 6) * 32);
            v8s bn = *(const v8s*)nb;
            if (ks == 0) {
                #pragma unroll
                for (int rt = 0; rt < 4; rt++)
                    acc[rt] = __builtin_amdgcn_mfma_f32_16x16x32_bf16(afrag[rt][0], bq0, zf, 0, 0, 0);
            } else {
                #pragma unroll
                for (int rt = 0; rt < 4; rt++)
                    acc[rt] = __builtin_amdgcn_mfma_f32_16x16x32_bf16(afrag[rt][ks], bq0, acc[rt], 0, 0, 0);
            }
            bq0 = bq1;
            bq1 = bn;
        }
        bp += (size_t)BN * DIM;

        #pragma unroll
        for (int rt = 0; rt < 4; rt++) {
            #pragma unroll
            for (int r = 0; r < 4; r++) {
                const int i = rt * 4 + r;
                top3_insert(acc[rt][r], t0[i], t1[i], t2[i]);
            }
        }
    }

    // merge across the 16 lanes (same rows, different col residues)
    #pragma unroll
    for (int step = 1; step < 16; step <<= 1) {
        #pragma unroll
        for (int i = 0; i < 16; i++) {
            float b0 = __shfl_xor(t0[i], step, 64);
            float b1 = __shfl_xor(t1[i], step, 64);
            float b2 = __shfl_xor(t2[i], step, 64);
            top3_insert(b0, t0[i], t1[i], t2[i]);
            top3_insert(b1, t0[i], t1[i], t2[i]);
            top3_insert(b2, t0[i], t1[i], t2[i]);
        }
    }

    if (lo == 0) {
        #pragma unroll
        for (int rt = 0; rt < 4; rt++) {
            #pragma unroll
            for (int r = 0; r < 4; r++) {
                const int i = rt * 4 + r;
                const int row = row0 + rt * 16 + quad * 4 + r;
                float* p = partial + ((size_t)row * NPART + (split * 4 + wave)) * 3;
                p[0] = t0[i]; p[1] = t1[i]; p[2] = t2[i];
            }
        }
    }
}

__global__ __launch_bounds__(256) void merge_kernel(
        const float* __restrict__ partial, float* __restrict__ out) {
    const int row = blockIdx.x * 256 + threadIdx.x;
    if (row >= N1) return;
    const float* p = partial + (size_t)row * NPART * 3;
    float t0 = -1e30f, t1 = -1e30f, t2 = -1e30f;
    #pragma unroll
    for (int i = 0; i < NPART * 3; i++) top3_insert(p[i], t0, t1, t2);
    out[row] = (t0 + t1 + t2) * (1.0f / 3.0f);
}

extern "C" void kernel_launch(void* const* d_in, const int* in_sizes, int n_in,
                              void* d_out, int out_size, void* d_ws, size_t ws_size,
                              hipStream_t stream) {
    const float* tA = (const float*)d_in[0];
    const float* tB = (const float*)d_in[1];
    float* out = (float*)d_out;

    __hip_bfloat16* An = (__hip_bfloat16*)d_ws;
    __hip_bfloat16* Bn = An + (size_t)N1 * DIM;
    float* partial = (float*)(Bn + (size_t)N2 * DIM);

    normalize_kernel<<<(N1 + N2) / 4, 256, 0, stream>>>(tA, tB, An, Bn);
    gemm_top3_kernel<<<(N1 / BM) * NSPLIT, 256, 0, stream>>>(An, Bn, partial);
    merge_kernel<<<N1 / 256, 256, 0, stream>>>(partial, out);
}